// Round 3
// baseline (319.108 us; speedup 1.0000x reference)
//
#include <hip/hip_runtime.h>
#include <math.h>

#define IMG_H 1080
#define IMG_W 1920
#define HW (IMG_H * IMG_W)
#define NBATCH 8

typedef float f4 __attribute__((ext_vector_type(4)));
typedef float f2 __attribute__((ext_vector_type(2)));

// JPEG base quant table (row-major 8x8)
__device__ __constant__ int BASEQ[64] = {
    16, 11, 10, 16, 24, 40, 51, 61,
    12, 12, 14, 19, 26, 58, 60, 55,
    14, 13, 16, 24, 40, 57, 69, 56,
    14, 17, 22, 29, 51, 87, 80, 62,
    18, 22, 37, 56, 68, 109, 103, 77,
    24, 35, 55, 64, 81, 104, 113, 92,
    49, 64, 78, 87, 103, 121, 120, 101,
    72, 92, 95, 98, 112, 100, 103, 99};

// Wave-internal LDS hand-off (no s_barrier anywhere in this kernel).
__device__ __forceinline__ void wave_lds_fence() {
    __builtin_amdgcn_wave_barrier();
    __builtin_amdgcn_s_waitcnt(0xC07F);  // vmcnt(63) expcnt(7) lgkmcnt(0)
    __builtin_amdgcn_wave_barrier();
}

__device__ __forceinline__ f2 splat2(float s) { f2 r = {s, s}; return r; }
__device__ __forceinline__ f2 pk_fma(f2 a, f2 b, f2 c) { return __builtin_elementwise_fma(a, b, c); }
// Exact c*x, immune to fmul+fadd contraction (fma with +0 addend; data makes
// sign-of-zero differences unobservable after the final add).
__device__ __forceinline__ f2 mul_nofuse(float c, f2 x) {
    f2 z = {0.0f, 0.0f};
    return __builtin_elementwise_fma(splat2(c), x, z);
}
__device__ __forceinline__ float uread(float v, int idx) {
    return __uint_as_float(__builtin_amdgcn_readlane(__float_as_uint(v), idx));
}
__device__ __forceinline__ f2 clamp2(f2 x) {
    f2 lo = {0.0f, 0.0f}, hi = {255.0f, 255.0f};
    return __builtin_elementwise_min(__builtin_elementwise_max(x, lo), hi);
}

// 192 threads = 3 independent waves; each wave owns an 8-row x 128-col strip
// (16 DCT blocks), 2 adjacent columns per lane processed as float2 (v_pk math).
__global__ __launch_bounds__(192) void h264_kernel(const float* __restrict__ x,
                                                   float* __restrict__ out) {
    __shared__ __align__(16) float yt[3 * 1024];  // per-wave 8x128 y / yd tile
    __shared__ __align__(16) float t2[3 * 1600];  // per-wave: 16 blk x (8 rows, stride 12, blk stride 100)
    __shared__ __align__(16) float blRM[64];      // basis row-major (setup only)
    __shared__ __align__(16) f2 PB[32];           // PB [j*8+m] = (B[2j][m], B[2j+1][m])
    __shared__ __align__(16) f2 PBc[32];          // PBc[j*8+m] = (B[m][2j], B[m][2j+1])
    __shared__ __align__(16) f2 QP[32];           // QP [j*8+k] = (Q[k][2j], Q[k][2j+1])
    __shared__ __align__(16) f2 RP[32];           // RP = 1/QP (correctly rounded)

    const int t = threadIdx.x;
    const int wave = t >> 6;
    const int lane = t & 63;

    // ---- basis value for this lane (row lane>>3, col lane&7), numpy f32 op order
    float v;
    {
        int k = lane >> 3, n = lane & 7;
        if (k == 0) {
            v = 0.35355339059327373f;  // np.sqrt(1/8)
        } else {
            float a = 3.14159265358979323846f * (float)k;  // f32(pi)*k
            a = a * (2.0f * (float)n + 1.0f);
            a = a / 16.0f;
            v = 0.5f * cosf(a);
        }
        blRM[lane] = v;
    }
    wave_lds_fence();
    // ---- pair tables (each wave writes identical values; benign duplicate writes)
    {
        int e = lane & 31;
        int j = e >> 3, m = e & 7;
        if (lane < 32) {
            f2 pbv = {blRM[16 * j + m], blRM[16 * j + 8 + m]};
            PB[e] = pbv;
            float qa = __fdiv_rn((float)(BASEQ[m * 8 + 2 * j] * 144), 50.0f);
            float qb = __fdiv_rn((float)(BASEQ[m * 8 + 2 * j + 1] * 144), 50.0f);
            f2 qv = {qa, qb};
            f2 rv = {__fdiv_rn(1.0f, qa), __fdiv_rn(1.0f, qb)};
            QP[e] = qv;
            RP[e] = rv;
        } else {
            f2 pcv = {blRM[m * 8 + 2 * j], blRM[m * 8 + 2 * j + 1]};
            PBc[e] = pcv;
        }
    }
    wave_lds_fence();

    const int h0 = blockIdx.y * 8;
    const int wcol0 = blockIdx.x * 384 + wave * 128;
    const float* xb = x + (size_t)blockIdx.z * 3 * HW;
    float* ob = out + (size_t)blockIdx.z * 3 * HW;
    float* ytw = yt + wave * 1024;
    float* t2w = t2 + wave * 1600;

    // ---- phase 1: nt f4 loads (kept in regs), luma -> LDS tile ----
    f4 Bv[4], Gv[4], Rv[4];
    int gaddr[4];
#pragma unroll
    for (int it = 0; it < 4; ++it) {
        int idx = lane + (it << 6);
        int row = idx >> 5;            // 8 rows x 32 f4/row
        int c4 = (idx & 31) << 2;
        int ga = (h0 + row) * IMG_W + wcol0 + c4;
        gaddr[it] = ga;
        Bv[it] = __builtin_nontemporal_load((const f4*)(xb + ga));
        Gv[it] = __builtin_nontemporal_load((const f4*)(xb + HW + ga));
        Rv[it] = __builtin_nontemporal_load((const f4*)(xb + 2 * HW + ga));
    }
#pragma unroll
    for (int it = 0; it < 4; ++it) {
        f2 b_l = {Bv[it].x, Bv[it].y}, b_h = {Bv[it].z, Bv[it].w};
        f2 g_l = {Gv[it].x, Gv[it].y}, g_h = {Gv[it].z, Gv[it].w};
        f2 r_l = {Rv[it].x, Rv[it].y}, r_h = {Rv[it].z, Rv[it].w};
        f2 ylo = (mul_nofuse(0.114f, b_l) + mul_nofuse(0.587f, g_l)) + mul_nofuse(0.299f, r_l);
        f2 yhi = (mul_nofuse(0.114f, b_h) + mul_nofuse(0.587f, g_h)) + mul_nofuse(0.299f, r_h);
        int idx = lane + (it << 6);
        int row = idx >> 5;
        int c4 = (idx & 31) << 2;
        f4 y4 = {ylo.x, ylo.y, yhi.x, yhi.y};
        *(f4*)(ytw + row * 128 + c4) = y4;
    }
    wave_lds_fence();

    // ---- phase 2: column DCT; lane owns cols (2*lane, 2*lane+1): block blk=lane>>2, pair j=lane&3
    const int blk = lane >> 2;
    const int j = lane & 3;
    float* t2b = t2w + blk * 100;

    f2 y2c[8];
#pragma unroll
    for (int i = 0; i < 8; ++i) y2c[i] = *(const f2*)(ytw + i * 128 + 2 * lane);

#pragma unroll
    for (int k = 0; k < 8; ++k) {
        f2 acc = {0.0f, 0.0f};
#pragma unroll
        for (int i = 0; i < 8; ++i) acc = pk_fma(splat2(uread(v, 8 * k + i)), y2c[i], acc);
        *(f2*)(t2b + k * 12 + 2 * j) = acc;  // T1 row-major
    }
    wave_lds_fence();

    // ---- phase 3: row DCT (reads T1 rows as b128) then quantize ----
    f2 pb[8];
    {
        const f4* p = (const f4*)(PB + 8 * j);
        f4 a0 = p[0], a1 = p[1], a2 = p[2], a3 = p[3];
        pb[0] = f2{a0.x, a0.y}; pb[1] = f2{a0.z, a0.w};
        pb[2] = f2{a1.x, a1.y}; pb[3] = f2{a1.z, a1.w};
        pb[4] = f2{a2.x, a2.y}; pb[5] = f2{a2.z, a2.w};
        pb[6] = f2{a3.x, a3.y}; pb[7] = f2{a3.z, a3.w};
    }
    f2 acc2[8];
#pragma unroll
    for (int k = 0; k < 8; ++k) {
        f4 ta = *(const f4*)(t2b + k * 12);
        f4 tb = *(const f4*)(t2b + k * 12 + 4);
        f2 acc = {0.0f, 0.0f};
        acc = pk_fma(splat2(ta.x), pb[0], acc);
        acc = pk_fma(splat2(ta.y), pb[1], acc);
        acc = pk_fma(splat2(ta.z), pb[2], acc);
        acc = pk_fma(splat2(ta.w), pb[3], acc);
        acc = pk_fma(splat2(tb.x), pb[4], acc);
        acc = pk_fma(splat2(tb.y), pb[5], acc);
        acc = pk_fma(splat2(tb.z), pb[6], acc);
        acc = pk_fma(splat2(tb.w), pb[7], acc);
        acc2[k] = acc;
    }
    wave_lds_fence();  // WAR: all T1 reads retired before C overwrite
    f2 qp_[8], rp_[8];
    {
        const f4* pq = (const f4*)(QP + 8 * j);
        const f4* pr = (const f4*)(RP + 8 * j);
        f4 a0 = pq[0], a1 = pq[1], a2 = pq[2], a3 = pq[3];
        qp_[0] = f2{a0.x, a0.y}; qp_[1] = f2{a0.z, a0.w};
        qp_[2] = f2{a1.x, a1.y}; qp_[3] = f2{a1.z, a1.w};
        qp_[4] = f2{a2.x, a2.y}; qp_[5] = f2{a2.z, a2.w};
        qp_[6] = f2{a3.x, a3.y}; qp_[7] = f2{a3.z, a3.w};
        f4 b0 = pr[0], b1 = pr[1], b2 = pr[2], b3 = pr[3];
        rp_[0] = f2{b0.x, b0.y}; rp_[1] = f2{b0.z, b0.w};
        rp_[2] = f2{b1.x, b1.y}; rp_[3] = f2{b1.z, b1.w};
        rp_[4] = f2{b2.x, b2.y}; rp_[5] = f2{b2.z, b2.w};
        rp_[6] = f2{b3.x, b3.y}; rp_[7] = f2{b3.z, b3.w};
    }
#pragma unroll
    for (int k = 0; k < 8; ++k) {
        f2 acc = acc2[k];
        // Markstein: correctly-rounded acc/q (== __fdiv_rn), 2 fma + 1 mul
        f2 q0 = acc * rp_[k];
        f2 e = pk_fma(-qp_[k], q0, acc);
        f2 q1 = pk_fma(e, rp_[k], q0);
        f2 n = {rintf(q1.x), rintf(q1.y)};  // round half-even == jnp.round
        f2 c = n * qp_[k];
        *(f2*)(t2b + k * 12 + 2 * j) = c;  // C row-major, overwrites T1
    }
    wave_lds_fence();

    // ---- phase 4: inverse DCT ----
    f2 pbc[8];
    {
        const f4* p = (const f4*)(PBc + 8 * j);
        f4 a0 = p[0], a1 = p[1], a2 = p[2], a3 = p[3];
        pbc[0] = f2{a0.x, a0.y}; pbc[1] = f2{a0.z, a0.w};
        pbc[2] = f2{a1.x, a1.y}; pbc[3] = f2{a1.z, a1.w};
        pbc[4] = f2{a2.x, a2.y}; pbc[5] = f2{a2.z, a2.w};
        pbc[6] = f2{a3.x, a3.y}; pbc[7] = f2{a3.z, a3.w};
    }
    f2 s2[8];
#pragma unroll
    for (int i = 0; i < 8; ++i) {
        f4 ca = *(const f4*)(t2b + i * 12);
        f4 cb = *(const f4*)(t2b + i * 12 + 4);
        f2 acc = {0.0f, 0.0f};
        acc = pk_fma(splat2(ca.x), pbc[0], acc);
        acc = pk_fma(splat2(ca.y), pbc[1], acc);
        acc = pk_fma(splat2(ca.z), pbc[2], acc);
        acc = pk_fma(splat2(ca.w), pbc[3], acc);
        acc = pk_fma(splat2(cb.x), pbc[4], acc);
        acc = pk_fma(splat2(cb.y), pbc[5], acc);
        acc = pk_fma(splat2(cb.z), pbc[6], acc);
        acc = pk_fma(splat2(cb.w), pbc[7], acc);
        s2[i] = acc;
    }
#pragma unroll
    for (int k = 0; k < 8; ++k) {
        f2 acc = {0.0f, 0.0f};
#pragma unroll
        for (int i = 0; i < 8; ++i) acc = pk_fma(splat2(uread(v, 8 * i + k)), s2[i], acc);
        f2 yd = acc - y2c[k];
        *(f2*)(ytw + k * 128 + 2 * lane) = yd;
    }
    wave_lds_fence();

    // ---- phase 5: epilogue from registered b/g/r; nt stores ----
#pragma unroll
    for (int it = 0; it < 4; ++it) {
        int idx = lane + (it << 6);
        int row = idx >> 5;
        int c4 = (idx & 31) << 2;
        f4 y4 = *(const f4*)(ytw + row * 128 + c4);
        f2 ylo = {y4.x, y4.y}, yhi = {y4.z, y4.w};
        int ga = gaddr[it];
        f2 t0, t1v;
        t0 = clamp2(f2{Bv[it].x, Bv[it].y} + mul_nofuse(0.114f, ylo));
        t1v = clamp2(f2{Bv[it].z, Bv[it].w} + mul_nofuse(0.114f, yhi));
        __builtin_nontemporal_store(f4{t0.x, t0.y, t1v.x, t1v.y}, (f4*)(ob + ga));
        t0 = clamp2(f2{Gv[it].x, Gv[it].y} + mul_nofuse(0.587f, ylo));
        t1v = clamp2(f2{Gv[it].z, Gv[it].w} + mul_nofuse(0.587f, yhi));
        __builtin_nontemporal_store(f4{t0.x, t0.y, t1v.x, t1v.y}, (f4*)(ob + HW + ga));
        t0 = clamp2(f2{Rv[it].x, Rv[it].y} + mul_nofuse(0.299f, ylo));
        t1v = clamp2(f2{Rv[it].z, Rv[it].w} + mul_nofuse(0.299f, yhi));
        __builtin_nontemporal_store(f4{t0.x, t0.y, t1v.x, t1v.y}, (f4*)(ob + 2 * HW + ga));
    }
}

extern "C" void kernel_launch(void* const* d_in, const int* in_sizes, int n_in,
                              void* d_out, int out_size, void* d_ws, size_t ws_size,
                              hipStream_t stream) {
    const float* x = (const float*)d_in[0];
    float* out = (float*)d_out;
    dim3 grid(IMG_W / 384, IMG_H / 8, NBATCH);  // 5 x 135 x 8
    dim3 block(192);
    h264_kernel<<<grid, block, 0, stream>>>(x, out);
}